// Round 12
// baseline (15867.586 us; speedup 1.0000x reference)
//
#include <hip/hip_runtime.h>
#include <math.h>

#define TSTEPS 4096
#define DIM 1024
#define GDIM 4096
#define ENC_NB 64
#define NREP 8
#define NSEG 64
#define SEGLEN 64

typedef short bf16x8 __attribute__((ext_vector_type(8)));
typedef float f32x4 __attribute__((ext_vector_type(4)));
typedef unsigned int uint4v __attribute__((ext_vector_type(4)));

__device__ __forceinline__ float sigmoidf_(float x) {
    return 1.0f / (1.0f + expf(-x));
}

__device__ __forceinline__ void pack8(const float* f, bf16x8& hi, bf16x8& lo)
{
    uint4v hw, lw;
    #pragma unroll
    for (int j = 0; j < 4; ++j) {
        unsigned u0 = __float_as_uint(f[2*j]);
        unsigned u1 = __float_as_uint(f[2*j+1]);
        unsigned m0 = u0 & 0xffff0000u;
        unsigned m1 = u1 & 0xffff0000u;
        float r0 = f[2*j]   - __uint_as_float(m0);
        float r1 = f[2*j+1] - __uint_as_float(m1);
        hw[j] = __builtin_amdgcn_perm(u1, u0, 0x07060302u);
        lw[j] = __builtin_amdgcn_perm(__float_as_uint(r1), __float_as_uint(r0),
                                      0x07060302u);
    }
    hi = __builtin_bit_cast(bf16x8, hw);
    lo = __builtin_bit_cast(bf16x8, lw);
}

// Load 8 consecutive fp32, split each into bf16 hi (truncate) + bf16 lo
// (truncated residual). x ~= hi + lo to ~2^-15 relative.
__device__ __forceinline__ void loadcvt(const float* __restrict__ p,
                                        bf16x8& hi, bf16x8& lo)
{
    float4 a = *(const float4*)p;
    float4 b = *(const float4*)(p + 4);
    float f[8] = {a.x, a.y, a.z, a.w, b.x, b.y, b.z, b.w};
    pack8(f, hi, lo);
}

// Same, but via agent-scope 8B atomic loads (bypasses possibly-stale local
// L2 — used for signal rows produced concurrently in the same kernel).
__device__ __forceinline__ void loadcvt_vis(const float* __restrict__ p,
                                            bf16x8& hi, bf16x8& lo)
{
    float f[8];
    #pragma unroll
    for (int i = 0; i < 4; ++i) {
        unsigned long long u = __hip_atomic_load(
            (const unsigned long long*)p + i, __ATOMIC_RELAXED,
            __HIP_MEMORY_SCOPE_AGENT);
        float2 f2 = __builtin_bit_cast(float2, u);
        f[2*i] = f2.x; f[2*i+1] = f2.y;
    }
    pack8(f, hi, lo);
}

// C[M,N] = A1[M,K]·B1[N,K]^T + bias1 + bias2  (Xenc pre-GEMM)
template<bool DUAL>
__global__ __launch_bounds__(256)
void gemm_split(const float* __restrict__ A1, const float* __restrict__ B1,
                const float* __restrict__ A2, const float* __restrict__ B2,
                const float* __restrict__ bias1, const float* __restrict__ bias2,
                float* __restrict__ C, int N)
{
    const int lane = threadIdx.x & 63;
    const int wid  = threadIdx.x >> 6;
    const int m0 = blockIdx.y * 128 + (wid >> 1) * 64;
    const int n0 = blockIdx.x * 128 + (wid & 1) * 64;
    const int rA   = m0 + (lane & 15);
    const int cB   = n0 + (lane & 15);
    const int koff = (lane >> 4) * 8;

    f32x4 acc[4][4] = {};

    const int npass = DUAL ? 2 : 1;
    for (int pass = 0; pass < npass; ++pass) {
        const float* __restrict__ A = (DUAL && pass) ? A2 : A1;
        const float* __restrict__ B = (DUAL && pass) ? B2 : B1;
        for (int k0 = 0; k0 < 1024; k0 += 32) {
            bf16x8 ah[4], al[4], bh[4], bl[4];
            #pragma unroll
            for (int i = 0; i < 4; ++i)
                loadcvt(A + (size_t)(rA + i * 16) * 1024 + k0 + koff, ah[i], al[i]);
            #pragma unroll
            for (int j = 0; j < 4; ++j)
                loadcvt(B + (size_t)(cB + j * 16) * 1024 + k0 + koff, bh[j], bl[j]);
            #pragma unroll
            for (int i = 0; i < 4; ++i)
                #pragma unroll
                for (int j = 0; j < 4; ++j) {
                    acc[i][j] = __builtin_amdgcn_mfma_f32_16x16x32_bf16(
                        ah[i], bh[j], acc[i][j], 0, 0, 0);
                    acc[i][j] = __builtin_amdgcn_mfma_f32_16x16x32_bf16(
                        ah[i], bl[j], acc[i][j], 0, 0, 0);
                    acc[i][j] = __builtin_amdgcn_mfma_f32_16x16x32_bf16(
                        al[i], bh[j], acc[i][j], 0, 0, 0);
                }
        }
    }

    const int er = (lane >> 4) * 4;
    const int ec = lane & 15;
    #pragma unroll
    for (int j = 0; j < 4; ++j) {
        int col = n0 + j * 16 + ec;
        float bb = bias1[col] + bias2[col];
        #pragma unroll
        for (int i = 0; i < 4; ++i) {
            int rowb = m0 + i * 16 + er;
            #pragma unroll
            for (int r = 0; r < 4; ++r)
                C[(size_t)(rowb + r) * N + col] = acc[i][j][r] + bb;
        }
    }
}

// ---------------- Mega-kernel: 256 blocks x 1024 threads, 1 block/CU.
// Residency forced by 88KB DYNAMIC LDS in the launch config (dispatch-packet
// group-segment size — cannot be DCE'd, unlike a dead static array).
// Blocks 0..63: encoder scan (r8 protocol, frozen) + per-channel progress
//   flags released every 256 steps; signal stored with agent-scope atomics.
// Blocks 64..255: DUAL-GEMM helpers. Work queue of 1024 tiles (128x128,
//   M-major). A tile waits until min(flags) >= min(m0+129, 4096):
//   (a) signal rows m0+1..m0+128 final+visible (row 4096 is memset zero),
//   (b) gates rows m0..m0+127 (old Xg) already consumed -> safe to overwrite.
__global__ __launch_bounds__(1024)
void mega_scan_gemm(const float* __restrict__ Xg,   // gates: Xenc in, Gdec out
                    const float* __restrict__ Whh,  // [4096][1024]
                    float* __restrict__ signal,     // [4097][1024]
                    unsigned long long* __restrict__ reps, // [8][2][1024] zeroed
                    float* __restrict__ l1_acc,
                    unsigned* __restrict__ flags,   // [1024] zeroed
                    const float* __restrict__ dWih, const float* __restrict__ dWhh,
                    const float* __restrict__ dbih, const float* __restrict__ dbhh,
                    const float* __restrict__ inputs,
                    float* __restrict__ gates,      // same buffer as Xg
                    unsigned* __restrict__ queue)   // [1] zeroed
{
    extern __shared__ float dyn_pad_[];   // sized at launch: occupancy limiter

    if (blockIdx.x < ENC_NB) {
        // ================= encoder scan (r8, frozen critical path) =========
        const int b = blockIdx.x;
        const int t = threadIdx.x;
        const int hbase = b * 16;
        const int w = t >> 6;
        const int j = t & 63;
        const int q = j >> 4;
        const int sub = j & 15;
        const int ch = hbase + w;
        const int grow = q * 1024 + ch;

        float4 wreg[16];
        {
            const float4* wrow = (const float4*)(Whh + (size_t)grow * 1024 + sub * 64);
            #pragma unroll
            for (int i = 0; i < 16; ++i) wreg[i] = wrow[i];
        }

        __shared__ float hls[2][16 * 68];
        __shared__ float hstage[16];

        unsigned long long* __restrict__ myrep =
            reps + (size_t)(b & (NREP - 1)) * 2 * 1024;

        float c = 0.f;
        float l1 = 0.f;

        for (int step = 0; step < TSTEPS; ++step) {
            const unsigned us = (unsigned)step;
            float xg = 0.f;
            if (sub == 0) xg = Xg[(size_t)step * GDIM + grow];

            const unsigned long long* sp = myrep + (size_t)(step & 1) * 1024 + t;
            unsigned long long v;
            while (true) {
                v = __hip_atomic_load(sp, __ATOMIC_RELAXED, __HIP_MEMORY_SCOPE_AGENT);
                if ((unsigned)(v >> 32) >= us) break;
                __builtin_amdgcn_s_sleep(1);
            }

            float* hb = hls[step & 1];
            hb[w * 68 + j] = __uint_as_float((unsigned)v);
            __syncthreads();                                   // barrier A

            float s = 0.f;
            const float* hv = hb + sub * 68;
            #pragma unroll
            for (int i = 0; i < 16; ++i) {
                float4 h4 = *(const float4*)(hv + i * 4);
                s = fmaf(wreg[i].x, h4.x, s); s = fmaf(wreg[i].y, h4.y, s);
                s = fmaf(wreg[i].z, h4.z, s); s = fmaf(wreg[i].w, h4.w, s);
            }
            s += __shfl_xor(s, 1);
            s += __shfl_xor(s, 2);
            s += __shfl_xor(s, 4);
            s += __shfl_xor(s, 8);

            float act = 0.f;
            if (sub == 0) {
                float pre = s + xg;
                act = (q == 2) ? tanhf(pre) : sigmoidf_(pre);
            }
            float fv = __shfl(act, 16);
            float gv = __shfl(act, 32);
            float ov = __shfl(act, 48);
            if (j == 0) {
                c = fmaf(fv, c, act * gv);
                hstage[w] = ov * tanhf(c);
            }
            __syncthreads();                                   // barrier B

            if (t < 16 * NREP) {
                const int rr = t >> 4, i = t & 15;
                float h = hstage[i];
                unsigned long long pv =
                    ((unsigned long long)(us + 1) << 32) | __float_as_uint(h);
                __hip_atomic_store(
                    reps + ((size_t)rr * 2 + ((step + 1) & 1)) * 1024 + hbase + i,
                    pv, __ATOMIC_RELAXED, __HIP_MEMORY_SCOPE_AGENT);
                if (t < 16) {
                    // agent-scope store: LLC-visible for streaming helpers
                    __hip_atomic_store(&signal[(size_t)step * DIM + hbase + t], h,
                                       __ATOMIC_RELAXED, __HIP_MEMORY_SCOPE_AGENT);
                    l1 += fabsf(h);
                    if ((step & 255) == 255) {
                        // release: orders this lane's prior signal stores
                        __hip_atomic_store(flags + hbase + t, us + 1,
                                           __ATOMIC_RELEASE, __HIP_MEMORY_SCOPE_AGENT);
                    }
                }
            }
        }
        if (t < 16) {
            #pragma unroll
            for (int off = 8; off >= 1; off >>= 1) l1 += __shfl_xor(l1, off);
            if (t == 0) atomicAdd(l1_acc, l1);
        }
    } else {
        // ================= DUAL-GEMM helper ================================
        const int tid  = threadIdx.x;
        const int wave = tid >> 6, lane = tid & 63;
        const int wm = (wave >> 2) * 32, wn = (wave & 3) * 32;
        const int r16 = lane & 15, koff = (lane >> 4) * 8;
        __shared__ unsigned s_qi;

        for (;;) {
            if (tid == 0) s_qi = atomicAdd(queue, 1u);
            __syncthreads();
            const unsigned qi = s_qi;
            __syncthreads();
            if (qi >= 1024u) break;
            const int m0 = (int)(qi >> 5) * 128;
            const int n0 = (int)(qi & 31) * 128;

            // wait: all scan blocks past step min(m0+128, 4095)
            {
                const unsigned need = (unsigned)min(m0 + 129, TSTEPS);
                if (wave == 0) {
                    while (true) {
                        unsigned mn = 0xffffffffu;
                        #pragma unroll
                        for (int k2 = 0; k2 < 16; ++k2) {
                            unsigned f = __hip_atomic_load(
                                flags + lane * 16 + k2, __ATOMIC_ACQUIRE,
                                __HIP_MEMORY_SCOPE_AGENT);
                            mn = min(mn, f);
                        }
                        #pragma unroll
                        for (int off = 32; off >= 1; off >>= 1)
                            mn = min(mn, (unsigned)__shfl_xor((int)mn, off));
                        if (mn >= need) break;
                        __builtin_amdgcn_s_sleep(16);
                    }
                }
                __syncthreads();
            }

            // DUAL 32x32 wave-tile: Gdec[m0+wm.., n0+wn..]
            f32x4 acc[2][2] = {};
            #pragma unroll
            for (int pass = 0; pass < 2; ++pass) {
                const float* __restrict__ A = pass ? inputs : (signal + DIM);
                const float* __restrict__ B = pass ? dWhh : dWih;
                for (int k0 = 0; k0 < 1024; k0 += 32) {
                    bf16x8 ah[2], al[2], bh[2], bl[2];
                    #pragma unroll
                    for (int i = 0; i < 2; ++i) {
                        const float* ap =
                            A + (size_t)(m0 + wm + i * 16 + r16) * 1024 + k0 + koff;
                        if (pass == 0) loadcvt_vis(ap, ah[i], al[i]);
                        else           loadcvt(ap, ah[i], al[i]);
                    }
                    #pragma unroll
                    for (int jj = 0; jj < 2; ++jj)
                        loadcvt(B + (size_t)(n0 + wn + jj * 16 + r16) * 1024 + k0 + koff,
                                bh[jj], bl[jj]);
                    #pragma unroll
                    for (int i = 0; i < 2; ++i)
                        #pragma unroll
                        for (int jj = 0; jj < 2; ++jj) {
                            acc[i][jj] = __builtin_amdgcn_mfma_f32_16x16x32_bf16(
                                ah[i], bh[jj], acc[i][jj], 0, 0, 0);
                            acc[i][jj] = __builtin_amdgcn_mfma_f32_16x16x32_bf16(
                                ah[i], bl[jj], acc[i][jj], 0, 0, 0);
                            acc[i][jj] = __builtin_amdgcn_mfma_f32_16x16x32_bf16(
                                al[i], bh[jj], acc[i][jj], 0, 0, 0);
                        }
                }
            }

            const int er = (lane >> 4) * 4, ec = lane & 15;
            #pragma unroll
            for (int jj = 0; jj < 2; ++jj) {
                int col = n0 + wn + jj * 16 + ec;
                float bb = dbih[col] + dbhh[col];
                #pragma unroll
                for (int i = 0; i < 2; ++i) {
                    int rowb = m0 + wm + i * 16 + er;
                    #pragma unroll
                    for (int r = 0; r < 4; ++r)
                        gates[(size_t)(rowb + r) * GDIM + col] = acc[i][jj][r] + bb;
                }
            }
        }
    }
}

// ---------------- Decoder: segmented affine scan. c_t = f_t*c + (i_t*g_t).
__global__ __launch_bounds__(256)
void dec_compose(const float* __restrict__ G, float* __restrict__ Aseg,
                 float* __restrict__ Bseg)
{
    const int j = blockIdx.x * 256 + threadIdx.x;
    const int s = blockIdx.y;
    const int t0 = s * SEGLEN;
    const int t1 = min(t0 + SEGLEN, TSTEPS - 1);
    float A = 1.f, Bv = 0.f;
    for (int t = t0; t < t1; ++t) {
        const float* g = G + (size_t)t * GDIM;
        float iv = sigmoidf_(g[j]);
        float fv = sigmoidf_(g[j + 1024]);
        float gv = tanhf(g[j + 2048]);
        A *= fv;
        Bv = fmaf(fv, Bv, iv * gv);
    }
    Aseg[s * DIM + j] = A;
    Bseg[s * DIM + j] = Bv;
}

__global__ __launch_bounds__(1024)
void dec_scan(const float* __restrict__ Aseg, const float* __restrict__ Bseg,
              float* __restrict__ cinit)
{
    const int j = threadIdx.x;
    float c = 0.f;
    for (int s = 0; s < NSEG; ++s) {
        cinit[s * DIM + j] = c;
        c = fmaf(Aseg[s * DIM + j], c, Bseg[s * DIM + j]);
    }
}

__global__ __launch_bounds__(256)
void dec_emit(const float* __restrict__ G, const float* __restrict__ inp,
              const float* __restrict__ cinit, float* __restrict__ mse_acc)
{
    const int j = blockIdx.x * 256 + threadIdx.x;
    const int s = blockIdx.y;
    const int t0 = s * SEGLEN;
    const int t1 = min(t0 + SEGLEN, TSTEPS - 1);
    float c = cinit[s * DIM + j];
    float acc = 0.f;
    for (int t = t0; t < t1; ++t) {
        const float* g = G + (size_t)t * GDIM;
        float iv = sigmoidf_(g[j]);
        float fv = sigmoidf_(g[j + 1024]);
        float gv = tanhf(g[j + 2048]);
        float ov = sigmoidf_(g[j + 3072]);
        c = fmaf(fv, c, iv * gv);
        float d = ov * tanhf(c);
        float diff = d - inp[(size_t)(t + 1) * DIM + j];
        acc = fmaf(diff, diff, acc);
    }
    #pragma unroll
    for (int off = 32; off >= 1; off >>= 1) acc += __shfl_xor(acc, off);
    if ((threadIdx.x & 63) == 0) atomicAdd(mse_acc, acc);
}

__global__ void finalize(const float* __restrict__ scal, float* __restrict__ out)
{
    float mse = scal[0] / ((float)(TSTEPS - 1) * (float)DIM);
    float l1  = scal[1] / ((float)TSTEPS * (float)DIM);
    out[0] = mse + 0.25f * l1;
    out[1] = mse;
    out[2] = l1;
}

extern "C" void kernel_launch(void* const* d_in, const int* in_sizes, int n_in,
                              void* d_out, int out_size, void* d_ws, size_t ws_size,
                              hipStream_t stream)
{
    const float* inputs  = (const float*)d_in[0];
    const float* enc_Wih = (const float*)d_in[1];
    const float* enc_Whh = (const float*)d_in[2];
    const float* enc_bih = (const float*)d_in[3];
    const float* enc_bhh = (const float*)d_in[4];
    const float* dec_Wih = (const float*)d_in[5];
    const float* dec_Whh = (const float*)d_in[6];
    const float* dec_bih = (const float*)d_in[7];
    const float* dec_bhh = (const float*)d_in[8];
    float* out = (float*)d_out;

    float* ws = (float*)d_ws;
    float* gates  = ws;                            // [4096][4096] Xenc then Gdec
    float* signal = ws + (size_t)16777216;         // [4097][1024] (row 4096 zero)
    unsigned long long* reps =
        (unsigned long long*)(ws + (size_t)20972544);   // [8][2][1024] u64
    float* scal   = ws + (size_t)21005312;         // [mse, l1] + pad
    unsigned* flags = (unsigned*)(ws + (size_t)21005320); // [1024]
    unsigned* queue = (unsigned*)(ws + (size_t)21006344); // [1] + pad
    // decoder scratch aliases signal (consumed by mega before dec_compose)
    float* Aseg   = signal;                        // [64][1024]
    float* Bseg   = signal + (size_t)65536;        // [64][1024]
    float* cinit  = signal + (size_t)131072;       // [64][1024]
    float* mse_acc = scal + 0;
    float* l1_acc  = scal + 1;

    // one memset: signal row 4096 + reps + scal + flags + queue
    hipMemsetAsync(ws + (size_t)20971520, 0,
                   (size_t)(1024 + 32768 + 8 + 1024 + 8) * 4, stream);

    dim3 b256(256);
    // Xenc = inputs @ enc_Wih^T + enc_bih + enc_bhh   (split-bf16 MFMA)
    gemm_split<false><<<dim3(32, 32), b256, 0, stream>>>(
        inputs, enc_Wih, nullptr, nullptr, enc_bih, enc_bhh, gates, GDIM);
    // mega: encoder scan (64 blocks) + streamed DUAL gemm (192 helper blocks);
    // 88KB dynamic LDS forces 1 block/CU (un-DCE-able occupancy limiter)
    mega_scan_gemm<<<dim3(256), dim3(1024), 90112, stream>>>(
        gates, enc_Whh, signal, reps, l1_acc, flags,
        dec_Wih, dec_Whh, dec_bih, dec_bhh, inputs, gates, queue);
    // decoder segmented scan + mse
    dec_compose<<<dim3(4, NSEG), b256, 0, stream>>>(gates, Aseg, Bseg);
    dec_scan<<<dim3(1), dim3(1024), 0, stream>>>(Aseg, Bseg, cinit);
    dec_emit<<<dim3(4, NSEG), b256, 0, stream>>>(gates, inputs, cinit, mse_acc);
    finalize<<<dim3(1), dim3(1), 0, stream>>>(scal, out);
}

// Round 13
// 15768.445 us; speedup vs baseline: 1.0063x; 1.0063x over previous
//
#include <hip/hip_runtime.h>
#include <math.h>

#define TSTEPS 4096
#define DIM 1024
#define GDIM 4096
#define ENC_NB 64
#define NREP 8
#define NSEG 64
#define SEGLEN 64

typedef short bf16x8 __attribute__((ext_vector_type(8)));
typedef float f32x4 __attribute__((ext_vector_type(4)));
typedef unsigned int uint4v __attribute__((ext_vector_type(4)));

__device__ __forceinline__ float sigmoidf_(float x) {
    return 1.0f / (1.0f + expf(-x));
}

__device__ __forceinline__ void pack8(const float* f, bf16x8& hi, bf16x8& lo)
{
    uint4v hw, lw;
    #pragma unroll
    for (int j = 0; j < 4; ++j) {
        unsigned u0 = __float_as_uint(f[2*j]);
        unsigned u1 = __float_as_uint(f[2*j+1]);
        unsigned m0 = u0 & 0xffff0000u;
        unsigned m1 = u1 & 0xffff0000u;
        float r0 = f[2*j]   - __uint_as_float(m0);
        float r1 = f[2*j+1] - __uint_as_float(m1);
        hw[j] = __builtin_amdgcn_perm(u1, u0, 0x07060302u);
        lw[j] = __builtin_amdgcn_perm(__float_as_uint(r1), __float_as_uint(r0),
                                      0x07060302u);
    }
    hi = __builtin_bit_cast(bf16x8, hw);
    lo = __builtin_bit_cast(bf16x8, lw);
}

// Load 8 consecutive fp32, split each into bf16 hi (truncate) + bf16 lo
// (truncated residual). x ~= hi + lo to ~2^-15 relative.
__device__ __forceinline__ void loadcvt(const float* __restrict__ p,
                                        bf16x8& hi, bf16x8& lo)
{
    float4 a = *(const float4*)p;
    float4 b = *(const float4*)(p + 4);
    float f[8] = {a.x, a.y, a.z, a.w, b.x, b.y, b.z, b.w};
    pack8(f, hi, lo);
}

// Same, but via agent-scope 8B atomic loads (bypasses possibly-stale local
// L2 — used for signal rows produced concurrently in the same kernel).
__device__ __forceinline__ void loadcvt_vis(const float* __restrict__ p,
                                            bf16x8& hi, bf16x8& lo)
{
    float f[8];
    #pragma unroll
    for (int i = 0; i < 4; ++i) {
        unsigned long long u = __hip_atomic_load(
            (const unsigned long long*)p + i, __ATOMIC_RELAXED,
            __HIP_MEMORY_SCOPE_AGENT);
        float2 f2 = __builtin_bit_cast(float2, u);
        f[2*i] = f2.x; f[2*i+1] = f2.y;
    }
    pack8(f, hi, lo);
}

// C[M,N] = A1[M,K]·B1[N,K]^T + bias1 + bias2  (Xenc pre-GEMM)
template<bool DUAL>
__global__ __launch_bounds__(256)
void gemm_split(const float* __restrict__ A1, const float* __restrict__ B1,
                const float* __restrict__ A2, const float* __restrict__ B2,
                const float* __restrict__ bias1, const float* __restrict__ bias2,
                float* __restrict__ C, int N)
{
    const int lane = threadIdx.x & 63;
    const int wid  = threadIdx.x >> 6;
    const int m0 = blockIdx.y * 128 + (wid >> 1) * 64;
    const int n0 = blockIdx.x * 128 + (wid & 1) * 64;
    const int rA   = m0 + (lane & 15);
    const int cB   = n0 + (lane & 15);
    const int koff = (lane >> 4) * 8;

    f32x4 acc[4][4] = {};

    const int npass = DUAL ? 2 : 1;
    for (int pass = 0; pass < npass; ++pass) {
        const float* __restrict__ A = (DUAL && pass) ? A2 : A1;
        const float* __restrict__ B = (DUAL && pass) ? B2 : B1;
        for (int k0 = 0; k0 < 1024; k0 += 32) {
            bf16x8 ah[4], al[4], bh[4], bl[4];
            #pragma unroll
            for (int i = 0; i < 4; ++i)
                loadcvt(A + (size_t)(rA + i * 16) * 1024 + k0 + koff, ah[i], al[i]);
            #pragma unroll
            for (int j = 0; j < 4; ++j)
                loadcvt(B + (size_t)(cB + j * 16) * 1024 + k0 + koff, bh[j], bl[j]);
            #pragma unroll
            for (int i = 0; i < 4; ++i)
                #pragma unroll
                for (int j = 0; j < 4; ++j) {
                    acc[i][j] = __builtin_amdgcn_mfma_f32_16x16x32_bf16(
                        ah[i], bh[j], acc[i][j], 0, 0, 0);
                    acc[i][j] = __builtin_amdgcn_mfma_f32_16x16x32_bf16(
                        ah[i], bl[j], acc[i][j], 0, 0, 0);
                    acc[i][j] = __builtin_amdgcn_mfma_f32_16x16x32_bf16(
                        al[i], bh[j], acc[i][j], 0, 0, 0);
                }
        }
    }

    const int er = (lane >> 4) * 4;
    const int ec = lane & 15;
    #pragma unroll
    for (int j = 0; j < 4; ++j) {
        int col = n0 + j * 16 + ec;
        float bb = bias1[col] + bias2[col];
        #pragma unroll
        for (int i = 0; i < 4; ++i) {
            int rowb = m0 + i * 16 + er;
            #pragma unroll
            for (int r = 0; r < 4; ++r)
                C[(size_t)(rowb + r) * N + col] = acc[i][j][r] + bb;
        }
    }
}

// ---------------- Mega-kernel: 256 blocks x 1024 threads, 1 block/CU.
// Residency forced by an 80KB STATIC LDS array touched via volatile stores
// (volatile cannot be DCE'd; static LDS has been honored in LDS_Block_Size
// every round — unlike the dead static array of r10 and the unused dynamic
// segment of r12).
// Blocks 0..63: encoder scan (r8 protocol, frozen) + per-channel progress
//   flags released every 256 steps; signal stored with agent-scope atomics.
// Blocks 64..255: DUAL-GEMM helpers. Work queue of 1024 tiles (128x128,
//   M-major). A tile waits until min(flags) >= min(m0+129, 4096):
//   (a) signal rows m0+1..m0+128 final+visible (row 4096 is memset zero),
//   (b) gates rows m0..m0+127 (old Xg) already consumed -> safe to overwrite.
__global__ __launch_bounds__(1024)
void mega_scan_gemm(const float* __restrict__ Xg,   // gates: Xenc in, Gdec out
                    const float* __restrict__ Whh,  // [4096][1024]
                    float* __restrict__ signal,     // [4097][1024]
                    unsigned long long* __restrict__ reps, // [8][2][1024] zeroed
                    float* __restrict__ l1_acc,
                    unsigned* __restrict__ flags,   // [1024] zeroed
                    const float* __restrict__ dWih, const float* __restrict__ dWhh,
                    const float* __restrict__ dbih, const float* __restrict__ dbhh,
                    const float* __restrict__ inputs,
                    float* __restrict__ gates,      // same buffer as Xg
                    unsigned* __restrict__ queue)   // [1] zeroed
{
    // 80KB occupancy limiter; volatile store = un-DCE-able liveness.
    __shared__ float lds_reserve[20480];
    ((volatile float*)lds_reserve)[threadIdx.x] = 0.f;

    if (blockIdx.x < ENC_NB) {
        // ================= encoder scan (r8, frozen critical path) =========
        const int b = blockIdx.x;
        const int t = threadIdx.x;
        const int hbase = b * 16;
        const int w = t >> 6;
        const int j = t & 63;
        const int q = j >> 4;
        const int sub = j & 15;
        const int ch = hbase + w;
        const int grow = q * 1024 + ch;

        float4 wreg[16];
        {
            const float4* wrow = (const float4*)(Whh + (size_t)grow * 1024 + sub * 64);
            #pragma unroll
            for (int i = 0; i < 16; ++i) wreg[i] = wrow[i];
        }

        __shared__ float hls[2][16 * 68];
        __shared__ float hstage[16];

        unsigned long long* __restrict__ myrep =
            reps + (size_t)(b & (NREP - 1)) * 2 * 1024;

        float c = 0.f;
        float l1 = 0.f;

        for (int step = 0; step < TSTEPS; ++step) {
            const unsigned us = (unsigned)step;
            float xg = 0.f;
            if (sub == 0) xg = Xg[(size_t)step * GDIM + grow];

            const unsigned long long* sp = myrep + (size_t)(step & 1) * 1024 + t;
            unsigned long long v;
            while (true) {
                v = __hip_atomic_load(sp, __ATOMIC_RELAXED, __HIP_MEMORY_SCOPE_AGENT);
                if ((unsigned)(v >> 32) >= us) break;
                __builtin_amdgcn_s_sleep(1);
            }

            float* hb = hls[step & 1];
            hb[w * 68 + j] = __uint_as_float((unsigned)v);
            __syncthreads();                                   // barrier A

            float s = 0.f;
            const float* hv = hb + sub * 68;
            #pragma unroll
            for (int i = 0; i < 16; ++i) {
                float4 h4 = *(const float4*)(hv + i * 4);
                s = fmaf(wreg[i].x, h4.x, s); s = fmaf(wreg[i].y, h4.y, s);
                s = fmaf(wreg[i].z, h4.z, s); s = fmaf(wreg[i].w, h4.w, s);
            }
            s += __shfl_xor(s, 1);
            s += __shfl_xor(s, 2);
            s += __shfl_xor(s, 4);
            s += __shfl_xor(s, 8);

            float act = 0.f;
            if (sub == 0) {
                float pre = s + xg;
                act = (q == 2) ? tanhf(pre) : sigmoidf_(pre);
            }
            float fv = __shfl(act, 16);
            float gv = __shfl(act, 32);
            float ov = __shfl(act, 48);
            if (j == 0) {
                c = fmaf(fv, c, act * gv);
                hstage[w] = ov * tanhf(c);
            }
            __syncthreads();                                   // barrier B

            if (t < 16 * NREP) {
                const int rr = t >> 4, i = t & 15;
                float h = hstage[i];
                unsigned long long pv =
                    ((unsigned long long)(us + 1) << 32) | __float_as_uint(h);
                __hip_atomic_store(
                    reps + ((size_t)rr * 2 + ((step + 1) & 1)) * 1024 + hbase + i,
                    pv, __ATOMIC_RELAXED, __HIP_MEMORY_SCOPE_AGENT);
                if (t < 16) {
                    // agent-scope store: LLC-visible for streaming helpers
                    __hip_atomic_store(&signal[(size_t)step * DIM + hbase + t], h,
                                       __ATOMIC_RELAXED, __HIP_MEMORY_SCOPE_AGENT);
                    l1 += fabsf(h);
                    if ((step & 255) == 255) {
                        // release: orders this lane's prior signal stores
                        __hip_atomic_store(flags + hbase + t, us + 1,
                                           __ATOMIC_RELEASE, __HIP_MEMORY_SCOPE_AGENT);
                    }
                }
            }
        }
        if (t < 16) {
            #pragma unroll
            for (int off = 8; off >= 1; off >>= 1) l1 += __shfl_xor(l1, off);
            if (t == 0) atomicAdd(l1_acc, l1);
        }
    } else {
        // ================= DUAL-GEMM helper ================================
        const int tid  = threadIdx.x;
        const int wave = tid >> 6, lane = tid & 63;
        const int wm = (wave >> 2) * 32, wn = (wave & 3) * 32;
        const int r16 = lane & 15, koff = (lane >> 4) * 8;
        __shared__ unsigned s_qi;

        for (;;) {
            if (tid == 0) s_qi = atomicAdd(queue, 1u);
            __syncthreads();
            const unsigned qi = s_qi;
            __syncthreads();
            if (qi >= 1024u) break;
            const int m0 = (int)(qi >> 5) * 128;
            const int n0 = (int)(qi & 31) * 128;

            // wait: all scan blocks past step min(m0+128, 4095)
            {
                const unsigned need = (unsigned)min(m0 + 129, TSTEPS);
                if (wave == 0) {
                    while (true) {
                        unsigned mn = 0xffffffffu;
                        #pragma unroll
                        for (int k2 = 0; k2 < 16; ++k2) {
                            unsigned f = __hip_atomic_load(
                                flags + lane * 16 + k2, __ATOMIC_ACQUIRE,
                                __HIP_MEMORY_SCOPE_AGENT);
                            mn = min(mn, f);
                        }
                        #pragma unroll
                        for (int off = 32; off >= 1; off >>= 1)
                            mn = min(mn, (unsigned)__shfl_xor((int)mn, off));
                        if (mn >= need) break;
                        __builtin_amdgcn_s_sleep(16);
                    }
                }
                __syncthreads();
            }

            // DUAL 32x32 wave-tile: Gdec[m0+wm.., n0+wn..]
            f32x4 acc[2][2] = {};
            #pragma unroll
            for (int pass = 0; pass < 2; ++pass) {
                const float* __restrict__ A = pass ? inputs : (signal + DIM);
                const float* __restrict__ B = pass ? dWhh : dWih;
                for (int k0 = 0; k0 < 1024; k0 += 32) {
                    bf16x8 ah[2], al[2], bh[2], bl[2];
                    #pragma unroll
                    for (int i = 0; i < 2; ++i) {
                        const float* ap =
                            A + (size_t)(m0 + wm + i * 16 + r16) * 1024 + k0 + koff;
                        if (pass == 0) loadcvt_vis(ap, ah[i], al[i]);
                        else           loadcvt(ap, ah[i], al[i]);
                    }
                    #pragma unroll
                    for (int jj = 0; jj < 2; ++jj)
                        loadcvt(B + (size_t)(n0 + wn + jj * 16 + r16) * 1024 + k0 + koff,
                                bh[jj], bl[jj]);
                    #pragma unroll
                    for (int i = 0; i < 2; ++i)
                        #pragma unroll
                        for (int jj = 0; jj < 2; ++jj) {
                            acc[i][jj] = __builtin_amdgcn_mfma_f32_16x16x32_bf16(
                                ah[i], bh[jj], acc[i][jj], 0, 0, 0);
                            acc[i][jj] = __builtin_amdgcn_mfma_f32_16x16x32_bf16(
                                ah[i], bl[jj], acc[i][jj], 0, 0, 0);
                            acc[i][jj] = __builtin_amdgcn_mfma_f32_16x16x32_bf16(
                                al[i], bh[jj], acc[i][jj], 0, 0, 0);
                        }
                }
            }

            const int er = (lane >> 4) * 4, ec = lane & 15;
            #pragma unroll
            for (int jj = 0; jj < 2; ++jj) {
                int col = n0 + wn + jj * 16 + ec;
                float bb = dbih[col] + dbhh[col];
                #pragma unroll
                for (int i = 0; i < 2; ++i) {
                    int rowb = m0 + wm + i * 16 + er;
                    #pragma unroll
                    for (int r = 0; r < 4; ++r)
                        gates[(size_t)(rowb + r) * GDIM + col] = acc[i][jj][r] + bb;
                }
            }
        }
    }
}

// ---------------- Decoder: segmented affine scan. c_t = f_t*c + (i_t*g_t).
__global__ __launch_bounds__(256)
void dec_compose(const float* __restrict__ G, float* __restrict__ Aseg,
                 float* __restrict__ Bseg)
{
    const int j = blockIdx.x * 256 + threadIdx.x;
    const int s = blockIdx.y;
    const int t0 = s * SEGLEN;
    const int t1 = min(t0 + SEGLEN, TSTEPS - 1);
    float A = 1.f, Bv = 0.f;
    for (int t = t0; t < t1; ++t) {
        const float* g = G + (size_t)t * GDIM;
        float iv = sigmoidf_(g[j]);
        float fv = sigmoidf_(g[j + 1024]);
        float gv = tanhf(g[j + 2048]);
        A *= fv;
        Bv = fmaf(fv, Bv, iv * gv);
    }
    Aseg[s * DIM + j] = A;
    Bseg[s * DIM + j] = Bv;
}

__global__ __launch_bounds__(1024)
void dec_scan(const float* __restrict__ Aseg, const float* __restrict__ Bseg,
              float* __restrict__ cinit)
{
    const int j = threadIdx.x;
    float c = 0.f;
    for (int s = 0; s < NSEG; ++s) {
        cinit[s * DIM + j] = c;
        c = fmaf(Aseg[s * DIM + j], c, Bseg[s * DIM + j]);
    }
}

__global__ __launch_bounds__(256)
void dec_emit(const float* __restrict__ G, const float* __restrict__ inp,
              const float* __restrict__ cinit, float* __restrict__ mse_acc)
{
    const int j = blockIdx.x * 256 + threadIdx.x;
    const int s = blockIdx.y;
    const int t0 = s * SEGLEN;
    const int t1 = min(t0 + SEGLEN, TSTEPS - 1);
    float c = cinit[s * DIM + j];
    float acc = 0.f;
    for (int t = t0; t < t1; ++t) {
        const float* g = G + (size_t)t * GDIM;
        float iv = sigmoidf_(g[j]);
        float fv = sigmoidf_(g[j + 1024]);
        float gv = tanhf(g[j + 2048]);
        float ov = sigmoidf_(g[j + 3072]);
        c = fmaf(fv, c, iv * gv);
        float d = ov * tanhf(c);
        float diff = d - inp[(size_t)(t + 1) * DIM + j];
        acc = fmaf(diff, diff, acc);
    }
    #pragma unroll
    for (int off = 32; off >= 1; off >>= 1) acc += __shfl_xor(acc, off);
    if ((threadIdx.x & 63) == 0) atomicAdd(mse_acc, acc);
}

__global__ void finalize(const float* __restrict__ scal, float* __restrict__ out)
{
    float mse = scal[0] / ((float)(TSTEPS - 1) * (float)DIM);
    float l1  = scal[1] / ((float)TSTEPS * (float)DIM);
    out[0] = mse + 0.25f * l1;
    out[1] = mse;
    out[2] = l1;
}

extern "C" void kernel_launch(void* const* d_in, const int* in_sizes, int n_in,
                              void* d_out, int out_size, void* d_ws, size_t ws_size,
                              hipStream_t stream)
{
    const float* inputs  = (const float*)d_in[0];
    const float* enc_Wih = (const float*)d_in[1];
    const float* enc_Whh = (const float*)d_in[2];
    const float* enc_bih = (const float*)d_in[3];
    const float* enc_bhh = (const float*)d_in[4];
    const float* dec_Wih = (const float*)d_in[5];
    const float* dec_Whh = (const float*)d_in[6];
    const float* dec_bih = (const float*)d_in[7];
    const float* dec_bhh = (const float*)d_in[8];
    float* out = (float*)d_out;

    float* ws = (float*)d_ws;
    float* gates  = ws;                            // [4096][4096] Xenc then Gdec
    float* signal = ws + (size_t)16777216;         // [4097][1024] (row 4096 zero)
    unsigned long long* reps =
        (unsigned long long*)(ws + (size_t)20972544);   // [8][2][1024] u64
    float* scal   = ws + (size_t)21005312;         // [mse, l1] + pad
    unsigned* flags = (unsigned*)(ws + (size_t)21005320); // [1024]
    unsigned* queue = (unsigned*)(ws + (size_t)21006344); // [1] + pad
    // decoder scratch aliases signal (consumed by mega before dec_compose)
    float* Aseg   = signal;                        // [64][1024]
    float* Bseg   = signal + (size_t)65536;        // [64][1024]
    float* cinit  = signal + (size_t)131072;       // [64][1024]
    float* mse_acc = scal + 0;
    float* l1_acc  = scal + 1;

    // one memset: signal row 4096 + reps + scal + flags + queue
    hipMemsetAsync(ws + (size_t)20971520, 0,
                   (size_t)(1024 + 32768 + 8 + 1024 + 8) * 4, stream);

    dim3 b256(256);
    // Xenc = inputs @ enc_Wih^T + enc_bih + enc_bhh   (split-bf16 MFMA)
    gemm_split<false><<<dim3(32, 32), b256, 0, stream>>>(
        inputs, enc_Wih, nullptr, nullptr, enc_bih, enc_bhh, gates, GDIM);
    // mega: encoder scan (64 blocks) + streamed DUAL gemm (192 helper blocks);
    // 80KB volatile-touched static LDS forces 1 block/CU
    mega_scan_gemm<<<dim3(256), dim3(1024), 0, stream>>>(
        gates, enc_Whh, signal, reps, l1_acc, flags,
        dec_Wih, dec_Whh, dec_bih, dec_bhh, inputs, gates, queue);
    // decoder segmented scan + mse
    dec_compose<<<dim3(4, NSEG), b256, 0, stream>>>(gates, Aseg, Bseg);
    dec_scan<<<dim3(1), dim3(1024), 0, stream>>>(Aseg, Bseg, cinit);
    dec_emit<<<dim3(4, NSEG), b256, 0, stream>>>(gates, inputs, cinit, mse_acc);
    finalize<<<dim3(1), dim3(1), 0, stream>>>(scal, out);
}

// Round 14
// 15720.543 us; speedup vs baseline: 1.0094x; 1.0030x over previous
//
#include <hip/hip_runtime.h>
#include <math.h>

#define TSTEPS 4096
#define DIM 1024
#define GDIM 4096
#define ENC_NB 64
#define NREP 8
#define NSEG 64
#define SEGLEN 64

typedef short bf16x8 __attribute__((ext_vector_type(8)));
typedef float f32x4 __attribute__((ext_vector_type(4)));
typedef unsigned int uint4v __attribute__((ext_vector_type(4)));

__device__ __forceinline__ float sigmoidf_(float x) {
    return 1.0f / (1.0f + expf(-x));
}

__device__ __forceinline__ void pack8(const float* f, bf16x8& hi, bf16x8& lo)
{
    uint4v hw, lw;
    #pragma unroll
    for (int j = 0; j < 4; ++j) {
        unsigned u0 = __float_as_uint(f[2*j]);
        unsigned u1 = __float_as_uint(f[2*j+1]);
        unsigned m0 = u0 & 0xffff0000u;
        unsigned m1 = u1 & 0xffff0000u;
        float r0 = f[2*j]   - __uint_as_float(m0);
        float r1 = f[2*j+1] - __uint_as_float(m1);
        hw[j] = __builtin_amdgcn_perm(u1, u0, 0x07060302u);
        lw[j] = __builtin_amdgcn_perm(__float_as_uint(r1), __float_as_uint(r0),
                                      0x07060302u);
    }
    hi = __builtin_bit_cast(bf16x8, hw);
    lo = __builtin_bit_cast(bf16x8, lw);
}

// Load 8 consecutive fp32, split each into bf16 hi (truncate) + bf16 lo
// (truncated residual). x ~= hi + lo to ~2^-15 relative.
__device__ __forceinline__ void loadcvt(const float* __restrict__ p,
                                        bf16x8& hi, bf16x8& lo)
{
    float4 a = *(const float4*)p;
    float4 b = *(const float4*)(p + 4);
    float f[8] = {a.x, a.y, a.z, a.w, b.x, b.y, b.z, b.w};
    pack8(f, hi, lo);
}

// C[M,N] = A1[M,K]·B1[N,K]^T + bias1 + bias2  (Xenc pre-GEMM)
template<bool DUAL>
__global__ __launch_bounds__(256)
void gemm_split(const float* __restrict__ A1, const float* __restrict__ B1,
                const float* __restrict__ A2, const float* __restrict__ B2,
                const float* __restrict__ bias1, const float* __restrict__ bias2,
                float* __restrict__ C, int N)
{
    const int lane = threadIdx.x & 63;
    const int wid  = threadIdx.x >> 6;
    const int m0 = blockIdx.y * 128 + (wid >> 1) * 64;
    const int n0 = blockIdx.x * 128 + (wid & 1) * 64;
    const int rA   = m0 + (lane & 15);
    const int cB   = n0 + (lane & 15);
    const int koff = (lane >> 4) * 8;

    f32x4 acc[4][4] = {};

    const int npass = DUAL ? 2 : 1;
    for (int pass = 0; pass < npass; ++pass) {
        const float* __restrict__ A = (DUAL && pass) ? A2 : A1;
        const float* __restrict__ B = (DUAL && pass) ? B2 : B1;
        for (int k0 = 0; k0 < 1024; k0 += 32) {
            bf16x8 ah[4], al[4], bh[4], bl[4];
            #pragma unroll
            for (int i = 0; i < 4; ++i)
                loadcvt(A + (size_t)(rA + i * 16) * 1024 + k0 + koff, ah[i], al[i]);
            #pragma unroll
            for (int j = 0; j < 4; ++j)
                loadcvt(B + (size_t)(cB + j * 16) * 1024 + k0 + koff, bh[j], bl[j]);
            #pragma unroll
            for (int i = 0; i < 4; ++i)
                #pragma unroll
                for (int j = 0; j < 4; ++j) {
                    acc[i][j] = __builtin_amdgcn_mfma_f32_16x16x32_bf16(
                        ah[i], bh[j], acc[i][j], 0, 0, 0);
                    acc[i][j] = __builtin_amdgcn_mfma_f32_16x16x32_bf16(
                        ah[i], bl[j], acc[i][j], 0, 0, 0);
                    acc[i][j] = __builtin_amdgcn_mfma_f32_16x16x32_bf16(
                        al[i], bh[j], acc[i][j], 0, 0, 0);
                }
        }
    }

    const int er = (lane >> 4) * 4;
    const int ec = lane & 15;
    #pragma unroll
    for (int j = 0; j < 4; ++j) {
        int col = n0 + j * 16 + ec;
        float bb = bias1[col] + bias2[col];
        #pragma unroll
        for (int i = 0; i < 4; ++i) {
            int rowb = m0 + i * 16 + er;
            #pragma unroll
            for (int r = 0; r < 4; ++r)
                C[(size_t)(rowb + r) * N + col] = acc[i][j][r] + bb;
        }
    }
}

// ---------------- Mega-kernel: 256 blocks x 1024 threads, 1 block/CU
// (80KB volatile-touched static LDS — verified honored in r13 counters).
// Blocks 0..63: encoder scan (r8 protocol, frozen) + per-channel progress
//   flags released every 256 steps; signal stored with agent-scope atomics.
// Blocks 64..255: DUAL-GEMM helpers. Work queue of 1024 tiles (128x128,
//   M-major). A tile waits until min(flags) >= min(m0+129, 4096):
//   (a) signal rows m0+1..m0+128 final+visible (row 4096 is memset zero),
//   (b) gates rows m0..m0+127 (old Xg) already consumed -> safe to overwrite.
// Helper signal reads are PLAIN cached loads (r13's 8B agent-atomic reads
// caused 67M tiny uncached transactions = 2.1GB HBM re-fetch and doubled the
// scan's exchange latency). Safe: dispatch acquire invalidates caches at
// launch; helpers never touch a signal line before its flag; producer stores
// go to LLC via agent scope -> no stale L2 copy can exist when first read.
__global__ __launch_bounds__(1024)
void mega_scan_gemm(const float* __restrict__ Xg,   // gates: Xenc in, Gdec out
                    const float* __restrict__ Whh,  // [4096][1024]
                    float* __restrict__ signal,     // [4097][1024]
                    unsigned long long* __restrict__ reps, // [8][2][1024] zeroed
                    float* __restrict__ l1_acc,
                    unsigned* __restrict__ flags,   // [1024] zeroed
                    const float* __restrict__ dWih, const float* __restrict__ dWhh,
                    const float* __restrict__ dbih, const float* __restrict__ dbhh,
                    const float* __restrict__ inputs,
                    float* __restrict__ gates,      // same buffer as Xg
                    unsigned* __restrict__ queue)   // [1] zeroed
{
    // 80KB occupancy limiter; volatile store = un-DCE-able liveness.
    __shared__ float lds_reserve[20480];
    ((volatile float*)lds_reserve)[threadIdx.x] = 0.f;

    if (blockIdx.x < ENC_NB) {
        // ================= encoder scan (r8, frozen critical path) =========
        const int b = blockIdx.x;
        const int t = threadIdx.x;
        const int hbase = b * 16;
        const int w = t >> 6;
        const int j = t & 63;
        const int q = j >> 4;
        const int sub = j & 15;
        const int ch = hbase + w;
        const int grow = q * 1024 + ch;

        float4 wreg[16];
        {
            const float4* wrow = (const float4*)(Whh + (size_t)grow * 1024 + sub * 64);
            #pragma unroll
            for (int i = 0; i < 16; ++i) wreg[i] = wrow[i];
        }

        __shared__ float hls[2][16 * 68];
        __shared__ float hstage[16];

        unsigned long long* __restrict__ myrep =
            reps + (size_t)(b & (NREP - 1)) * 2 * 1024;

        float c = 0.f;
        float l1 = 0.f;

        for (int step = 0; step < TSTEPS; ++step) {
            const unsigned us = (unsigned)step;
            float xg = 0.f;
            if (sub == 0) xg = Xg[(size_t)step * GDIM + grow];

            const unsigned long long* sp = myrep + (size_t)(step & 1) * 1024 + t;
            unsigned long long v;
            while (true) {
                v = __hip_atomic_load(sp, __ATOMIC_RELAXED, __HIP_MEMORY_SCOPE_AGENT);
                if ((unsigned)(v >> 32) >= us) break;
                __builtin_amdgcn_s_sleep(1);
            }

            float* hb = hls[step & 1];
            hb[w * 68 + j] = __uint_as_float((unsigned)v);
            __syncthreads();                                   // barrier A

            float s = 0.f;
            const float* hv = hb + sub * 68;
            #pragma unroll
            for (int i = 0; i < 16; ++i) {
                float4 h4 = *(const float4*)(hv + i * 4);
                s = fmaf(wreg[i].x, h4.x, s); s = fmaf(wreg[i].y, h4.y, s);
                s = fmaf(wreg[i].z, h4.z, s); s = fmaf(wreg[i].w, h4.w, s);
            }
            s += __shfl_xor(s, 1);
            s += __shfl_xor(s, 2);
            s += __shfl_xor(s, 4);
            s += __shfl_xor(s, 8);

            float act = 0.f;
            if (sub == 0) {
                float pre = s + xg;
                act = (q == 2) ? tanhf(pre) : sigmoidf_(pre);
            }
            float fv = __shfl(act, 16);
            float gv = __shfl(act, 32);
            float ov = __shfl(act, 48);
            if (j == 0) {
                c = fmaf(fv, c, act * gv);
                hstage[w] = ov * tanhf(c);
            }
            __syncthreads();                                   // barrier B

            if (t < 16 * NREP) {
                const int rr = t >> 4, i = t & 15;
                float h = hstage[i];
                unsigned long long pv =
                    ((unsigned long long)(us + 1) << 32) | __float_as_uint(h);
                __hip_atomic_store(
                    reps + ((size_t)rr * 2 + ((step + 1) & 1)) * 1024 + hbase + i,
                    pv, __ATOMIC_RELAXED, __HIP_MEMORY_SCOPE_AGENT);
                if (t < 16) {
                    // agent-scope store: LLC-visible for streaming helpers
                    __hip_atomic_store(&signal[(size_t)step * DIM + hbase + t], h,
                                       __ATOMIC_RELAXED, __HIP_MEMORY_SCOPE_AGENT);
                    l1 += fabsf(h);
                    if ((step & 255) == 255) {
                        // release: orders this lane's prior signal stores
                        __hip_atomic_store(flags + hbase + t, us + 1,
                                           __ATOMIC_RELEASE, __HIP_MEMORY_SCOPE_AGENT);
                    }
                }
            }
        }
        if (t < 16) {
            #pragma unroll
            for (int off = 8; off >= 1; off >>= 1) l1 += __shfl_xor(l1, off);
            if (t == 0) atomicAdd(l1_acc, l1);
        }
    } else {
        // ================= DUAL-GEMM helper ================================
        const int tid  = threadIdx.x;
        const int wave = tid >> 6, lane = tid & 63;
        const int wm = (wave >> 2) * 32, wn = (wave & 3) * 32;
        const int r16 = lane & 15, koff = (lane >> 4) * 8;
        __shared__ unsigned s_qi;

        for (;;) {
            if (tid == 0) s_qi = atomicAdd(queue, 1u);
            __syncthreads();
            const unsigned qi = s_qi;
            __syncthreads();
            if (qi >= 1024u) break;
            const int m0 = (int)(qi >> 5) * 128;
            const int n0 = (int)(qi & 31) * 128;

            // wait: all scan blocks past step min(m0+128, 4095)
            {
                const unsigned need = (unsigned)min(m0 + 129, TSTEPS);
                if (wave == 0) {
                    while (true) {
                        unsigned mn = 0xffffffffu;
                        #pragma unroll
                        for (int k2 = 0; k2 < 16; ++k2) {
                            unsigned f = __hip_atomic_load(
                                flags + lane * 16 + k2, __ATOMIC_ACQUIRE,
                                __HIP_MEMORY_SCOPE_AGENT);
                            mn = min(mn, f);
                        }
                        #pragma unroll
                        for (int off = 32; off >= 1; off >>= 1)
                            mn = min(mn, (unsigned)__shfl_xor((int)mn, off));
                        if (mn >= need) break;
                        __builtin_amdgcn_s_sleep(64);
                    }
                }
                __syncthreads();
            }

            // DUAL 32x32 wave-tile: Gdec[m0+wm.., n0+wn..]
            f32x4 acc[2][2] = {};
            #pragma unroll
            for (int pass = 0; pass < 2; ++pass) {
                const float* __restrict__ A = pass ? inputs : (signal + DIM);
                const float* __restrict__ B = pass ? dWhh : dWih;
                for (int k0 = 0; k0 < 1024; k0 += 32) {
                    bf16x8 ah[2], al[2], bh[2], bl[2];
                    #pragma unroll
                    for (int i = 0; i < 2; ++i)
                        loadcvt(A + (size_t)(m0 + wm + i * 16 + r16) * 1024 + k0 + koff,
                                ah[i], al[i]);
                    #pragma unroll
                    for (int jj = 0; jj < 2; ++jj)
                        loadcvt(B + (size_t)(n0 + wn + jj * 16 + r16) * 1024 + k0 + koff,
                                bh[jj], bl[jj]);
                    #pragma unroll
                    for (int i = 0; i < 2; ++i)
                        #pragma unroll
                        for (int jj = 0; jj < 2; ++jj) {
                            acc[i][jj] = __builtin_amdgcn_mfma_f32_16x16x32_bf16(
                                ah[i], bh[jj], acc[i][jj], 0, 0, 0);
                            acc[i][jj] = __builtin_amdgcn_mfma_f32_16x16x32_bf16(
                                ah[i], bl[jj], acc[i][jj], 0, 0, 0);
                            acc[i][jj] = __builtin_amdgcn_mfma_f32_16x16x32_bf16(
                                al[i], bh[jj], acc[i][jj], 0, 0, 0);
                        }
                }
            }

            const int er = (lane >> 4) * 4, ec = lane & 15;
            #pragma unroll
            for (int jj = 0; jj < 2; ++jj) {
                int col = n0 + wn + jj * 16 + ec;
                float bb = dbih[col] + dbhh[col];
                #pragma unroll
                for (int i = 0; i < 2; ++i) {
                    int rowb = m0 + wm + i * 16 + er;
                    #pragma unroll
                    for (int r = 0; r < 4; ++r)
                        gates[(size_t)(rowb + r) * GDIM + col] = acc[i][jj][r] + bb;
                }
            }
        }
    }
}

// ---------------- Decoder: segmented affine scan. c_t = f_t*c + (i_t*g_t).
__global__ __launch_bounds__(256)
void dec_compose(const float* __restrict__ G, float* __restrict__ Aseg,
                 float* __restrict__ Bseg)
{
    const int j = blockIdx.x * 256 + threadIdx.x;
    const int s = blockIdx.y;
    const int t0 = s * SEGLEN;
    const int t1 = min(t0 + SEGLEN, TSTEPS - 1);
    float A = 1.f, Bv = 0.f;
    for (int t = t0; t < t1; ++t) {
        const float* g = G + (size_t)t * GDIM;
        float iv = sigmoidf_(g[j]);
        float fv = sigmoidf_(g[j + 1024]);
        float gv = tanhf(g[j + 2048]);
        A *= fv;
        Bv = fmaf(fv, Bv, iv * gv);
    }
    Aseg[s * DIM + j] = A;
    Bseg[s * DIM + j] = Bv;
}

__global__ __launch_bounds__(1024)
void dec_scan(const float* __restrict__ Aseg, const float* __restrict__ Bseg,
              float* __restrict__ cinit)
{
    const int j = threadIdx.x;
    float c = 0.f;
    for (int s = 0; s < NSEG; ++s) {
        cinit[s * DIM + j] = c;
        c = fmaf(Aseg[s * DIM + j], c, Bseg[s * DIM + j]);
    }
}

__global__ __launch_bounds__(256)
void dec_emit(const float* __restrict__ G, const float* __restrict__ inp,
              const float* __restrict__ cinit, float* __restrict__ mse_acc)
{
    const int j = blockIdx.x * 256 + threadIdx.x;
    const int s = blockIdx.y;
    const int t0 = s * SEGLEN;
    const int t1 = min(t0 + SEGLEN, TSTEPS - 1);
    float c = cinit[s * DIM + j];
    float acc = 0.f;
    for (int t = t0; t < t1; ++t) {
        const float* g = G + (size_t)t * GDIM;
        float iv = sigmoidf_(g[j]);
        float fv = sigmoidf_(g[j + 1024]);
        float gv = tanhf(g[j + 2048]);
        float ov = sigmoidf_(g[j + 3072]);
        c = fmaf(fv, c, iv * gv);
        float d = ov * tanhf(c);
        float diff = d - inp[(size_t)(t + 1) * DIM + j];
        acc = fmaf(diff, diff, acc);
    }
    #pragma unroll
    for (int off = 32; off >= 1; off >>= 1) acc += __shfl_xor(acc, off);
    if ((threadIdx.x & 63) == 0) atomicAdd(mse_acc, acc);
}

__global__ void finalize(const float* __restrict__ scal, float* __restrict__ out)
{
    float mse = scal[0] / ((float)(TSTEPS - 1) * (float)DIM);
    float l1  = scal[1] / ((float)TSTEPS * (float)DIM);
    out[0] = mse + 0.25f * l1;
    out[1] = mse;
    out[2] = l1;
}

extern "C" void kernel_launch(void* const* d_in, const int* in_sizes, int n_in,
                              void* d_out, int out_size, void* d_ws, size_t ws_size,
                              hipStream_t stream)
{
    const float* inputs  = (const float*)d_in[0];
    const float* enc_Wih = (const float*)d_in[1];
    const float* enc_Whh = (const float*)d_in[2];
    const float* enc_bih = (const float*)d_in[3];
    const float* enc_bhh = (const float*)d_in[4];
    const float* dec_Wih = (const float*)d_in[5];
    const float* dec_Whh = (const float*)d_in[6];
    const float* dec_bih = (const float*)d_in[7];
    const float* dec_bhh = (const float*)d_in[8];
    float* out = (float*)d_out;

    float* ws = (float*)d_ws;
    float* gates  = ws;                            // [4096][4096] Xenc then Gdec
    float* signal = ws + (size_t)16777216;         // [4097][1024] (row 4096 zero)
    unsigned long long* reps =
        (unsigned long long*)(ws + (size_t)20972544);   // [8][2][1024] u64
    float* scal   = ws + (size_t)21005312;         // [mse, l1] + pad
    unsigned* flags = (unsigned*)(ws + (size_t)21005320); // [1024]
    unsigned* queue = (unsigned*)(ws + (size_t)21006344); // [1] + pad
    // decoder scratch aliases signal (consumed by mega before dec_compose)
    float* Aseg   = signal;                        // [64][1024]
    float* Bseg   = signal + (size_t)65536;        // [64][1024]
    float* cinit  = signal + (size_t)131072;       // [64][1024]
    float* mse_acc = scal + 0;
    float* l1_acc  = scal + 1;

    // one memset: signal row 4096 + reps + scal + flags + queue
    hipMemsetAsync(ws + (size_t)20971520, 0,
                   (size_t)(1024 + 32768 + 8 + 1024 + 8) * 4, stream);

    dim3 b256(256);
    // Xenc = inputs @ enc_Wih^T + enc_bih + enc_bhh   (split-bf16 MFMA)
    gemm_split<false><<<dim3(32, 32), b256, 0, stream>>>(
        inputs, enc_Wih, nullptr, nullptr, enc_bih, enc_bhh, gates, GDIM);
    // mega: encoder scan (64 blocks) + streamed DUAL gemm (192 helper blocks)
    mega_scan_gemm<<<dim3(256), dim3(1024), 0, stream>>>(
        gates, enc_Whh, signal, reps, l1_acc, flags,
        dec_Wih, dec_Whh, dec_bih, dec_bhh, inputs, gates, queue);
    // decoder segmented scan + mse
    dec_compose<<<dim3(4, NSEG), b256, 0, stream>>>(gates, Aseg, Bseg);
    dec_scan<<<dim3(1), dim3(1024), 0, stream>>>(Aseg, Bseg, cinit);
    dec_emit<<<dim3(4, NSEG), b256, 0, stream>>>(gates, inputs, cinit, mse_acc);
    finalize<<<dim3(1), dim3(1), 0, stream>>>(scal, out);
}

// Round 15
// 8778.945 us; speedup vs baseline: 1.8075x; 1.7907x over previous
//
#include <hip/hip_runtime.h>
#include <math.h>

#define TSTEPS 4096
#define DIM 1024
#define GDIM 4096
#define ENC_NB 64
#define NREP 8
#define NSEG 64
#define SEGLEN 64

typedef short bf16x8 __attribute__((ext_vector_type(8)));
typedef float f32x4 __attribute__((ext_vector_type(4)));
typedef unsigned int uint4v __attribute__((ext_vector_type(4)));

__device__ __forceinline__ float sigmoidf_(float x) {
    return 1.0f / (1.0f + expf(-x));
}

// Load 8 consecutive fp32, split each into bf16 hi (truncate) + bf16 lo
// (truncated residual). x ~= hi + lo to ~2^-15 relative.
__device__ __forceinline__ void loadcvt(const float* __restrict__ p,
                                        bf16x8& hi, bf16x8& lo)
{
    float4 a = *(const float4*)p;
    float4 b = *(const float4*)(p + 4);
    float f[8] = {a.x, a.y, a.z, a.w, b.x, b.y, b.z, b.w};
    uint4v hw, lw;
    #pragma unroll
    for (int j = 0; j < 4; ++j) {
        unsigned u0 = __float_as_uint(f[2*j]);
        unsigned u1 = __float_as_uint(f[2*j+1]);
        unsigned m0 = u0 & 0xffff0000u;
        unsigned m1 = u1 & 0xffff0000u;
        float r0 = f[2*j]   - __uint_as_float(m0);
        float r1 = f[2*j+1] - __uint_as_float(m1);
        hw[j] = __builtin_amdgcn_perm(u1, u0, 0x07060302u);
        lw[j] = __builtin_amdgcn_perm(__float_as_uint(r1), __float_as_uint(r0),
                                      0x07060302u);
    }
    hi = __builtin_bit_cast(bf16x8, hw);
    lo = __builtin_bit_cast(bf16x8, lw);
}

// C[M,N] = A1[M,K]·B1[N,K]^T (+ A2·B2^T if DUAL) + bias1 + bias2
template<bool DUAL>
__global__ __launch_bounds__(256)
void gemm_split(const float* __restrict__ A1, const float* __restrict__ B1,
                const float* __restrict__ A2, const float* __restrict__ B2,
                const float* __restrict__ bias1, const float* __restrict__ bias2,
                float* __restrict__ C, int N)
{
    const int lane = threadIdx.x & 63;
    const int wid  = threadIdx.x >> 6;
    const int m0 = blockIdx.y * 128 + (wid >> 1) * 64;
    const int n0 = blockIdx.x * 128 + (wid & 1) * 64;
    const int rA   = m0 + (lane & 15);
    const int cB   = n0 + (lane & 15);
    const int koff = (lane >> 4) * 8;

    f32x4 acc[4][4] = {};

    const int npass = DUAL ? 2 : 1;
    for (int pass = 0; pass < npass; ++pass) {
        const float* __restrict__ A = (DUAL && pass) ? A2 : A1;
        const float* __restrict__ B = (DUAL && pass) ? B2 : B1;
        for (int k0 = 0; k0 < 1024; k0 += 32) {
            bf16x8 ah[4], al[4], bh[4], bl[4];
            #pragma unroll
            for (int i = 0; i < 4; ++i)
                loadcvt(A + (size_t)(rA + i * 16) * 1024 + k0 + koff, ah[i], al[i]);
            #pragma unroll
            for (int j = 0; j < 4; ++j)
                loadcvt(B + (size_t)(cB + j * 16) * 1024 + k0 + koff, bh[j], bl[j]);
            #pragma unroll
            for (int i = 0; i < 4; ++i)
                #pragma unroll
                for (int j = 0; j < 4; ++j) {
                    acc[i][j] = __builtin_amdgcn_mfma_f32_16x16x32_bf16(
                        ah[i], bh[j], acc[i][j], 0, 0, 0);
                    acc[i][j] = __builtin_amdgcn_mfma_f32_16x16x32_bf16(
                        ah[i], bl[j], acc[i][j], 0, 0, 0);
                    acc[i][j] = __builtin_amdgcn_mfma_f32_16x16x32_bf16(
                        al[i], bh[j], acc[i][j], 0, 0, 0);
                }
        }
    }

    const int er = (lane >> 4) * 4;
    const int ec = lane & 15;
    #pragma unroll
    for (int j = 0; j < 4; ++j) {
        int col = n0 + j * 16 + ec;
        float bb = bias1[col] + bias2[col];
        #pragma unroll
        for (int i = 0; i < 4; ++i) {
            int rowb = m0 + i * 16 + er;
            #pragma unroll
            for (int r = 0; r < 4; ++r)
                C[(size_t)(rowb + r) * N + col] = acc[i][j][r] + bb;
        }
    }
}

// ---------------- Encoder sequential scan, wave-per-channel, 8x replicated
// slot arrays. 64 blocks x 1024 threads (16 waves). Wave w owns channel
// hbase+w. Lane j: gate q=j>>4, k-chunk sub=j&15. Whh in 16 float4 regs.
// Exchange: fused tag|payload 8B words in reps[r][parity][1024]. Publisher
// block writes its 128B line into ALL 8 replicas (threads t<128, one store
// each, parallel banks). Consumer block g polls ONLY replica g&7 -> pollers
// per cache line drop 1024 -> 128.
// Safety (2-epoch induction, per replica): block b writes (s+2, parity P)
// only after b detected s+1 from every publisher, which requires every
// block to have published s+1, which requires all their waves passed
// barrier A(s), i.e. every consuming load of (s, P) already completed.
__global__ __launch_bounds__(1024)
void encoder_scan(const float* __restrict__ Xg,   // [4096][4096]
                  const float* __restrict__ Whh,  // [4096][1024]
                  float* __restrict__ signal,     // [4097][1024]
                  unsigned long long* __restrict__ reps,  // [8][2][1024] zeroed
                  float* __restrict__ l1_acc)
{
    const int b = blockIdx.x;
    const int t = threadIdx.x;
    const int hbase = b * 16;
    const int w = t >> 6;        // wave index = channel offset
    const int j = t & 63;        // lane
    const int q = j >> 4;        // gate 0..3
    const int sub = j & 15;      // k-chunk 0..15
    const int ch = hbase + w;
    const int grow = q * 1024 + ch;

    float4 wreg[16];
    {
        const float4* wrow = (const float4*)(Whh + (size_t)grow * 1024 + sub * 64);
        #pragma unroll
        for (int i = 0; i < 16; ++i) wreg[i] = wrow[i];
    }

    __shared__ float hls[2][16 * 68];  // [parity][chunk*68 + elem]
    __shared__ float hstage[16];

    // my poll replica
    unsigned long long* __restrict__ myrep =
        reps + (size_t)(b & (NREP - 1)) * 2 * 1024;

    float c = 0.f;   // channel cell state, lane 0 of each wave
    float l1 = 0.f;  // t<16 only

    for (int step = 0; step < TSTEPS; ++step) {
        const unsigned us = (unsigned)step;
        // prefetch Xg for the 4 gate lanes (hides under poll)
        float xg = 0.f;
        if (sub == 0) xg = Xg[(size_t)step * GDIM + grow];

        // single-load sleep-throttled poll on own slot of own replica
        const unsigned long long* sp = myrep + (size_t)(step & 1) * 1024 + t;
        unsigned long long v;
        while (true) {
            v = __hip_atomic_load(sp, __ATOMIC_RELAXED, __HIP_MEMORY_SCOPE_AGENT);
            if ((unsigned)(v >> 32) >= us) break;
            __builtin_amdgcn_s_sleep(1);
        }

        float* hb = hls[step & 1];
        hb[w * 68 + j] = __uint_as_float((unsigned)v);
        __syncthreads();                                   // barrier A

        // dot: 64 register FMAs against LDS chunk `sub`
        float s = 0.f;
        const float* hv = hb + sub * 68;
        #pragma unroll
        for (int i = 0; i < 16; ++i) {
            float4 h4 = *(const float4*)(hv + i * 4);
            s = fmaf(wreg[i].x, h4.x, s); s = fmaf(wreg[i].y, h4.y, s);
            s = fmaf(wreg[i].z, h4.z, s); s = fmaf(wreg[i].w, h4.w, s);
        }
        s += __shfl_xor(s, 1);
        s += __shfl_xor(s, 2);
        s += __shfl_xor(s, 4);
        s += __shfl_xor(s, 8);

        // parallel activations at the 4 gate lanes (j = 0,16,32,48)
        float act = 0.f;
        if (sub == 0) {
            float pre = s + xg;
            act = (q == 2) ? tanhf(pre) : sigmoidf_(pre);
        }
        float fv = __shfl(act, 16);
        float gv = __shfl(act, 32);
        float ov = __shfl(act, 48);
        if (j == 0) {
            c = fmaf(fv, c, act * gv);   // act = iv at lane 0
            hstage[w] = ov * tanhf(c);
        }
        __syncthreads();                                   // barrier B

        // replicated publish: threads t<128, replica r=t>>4, slot i=t&15.
        // 8 coalesced 128B line-stores to 8 different banks, in parallel.
        if (t < 16 * NREP) {
            const int rr = t >> 4, i = t & 15;
            float h = hstage[i];
            unsigned long long pv =
                ((unsigned long long)(us + 1) << 32) | __float_as_uint(h);
            __hip_atomic_store(
                reps + ((size_t)rr * 2 + ((step + 1) & 1)) * 1024 + hbase + i,
                pv, __ATOMIC_RELAXED, __HIP_MEMORY_SCOPE_AGENT);
            if (t < 16) {
                signal[(size_t)step * DIM + hbase + t] = h;
                l1 += fabsf(h);
            }
        }
    }
    if (t < 16) {
        #pragma unroll
        for (int off = 8; off >= 1; off >>= 1) l1 += __shfl_xor(l1, off);
        if (t == 0) atomicAdd(l1_acc, l1);
    }
}

// ---------------- Decoder: segmented affine scan. c_t = f_t*c + (i_t*g_t).
__global__ __launch_bounds__(256)
void dec_compose(const float* __restrict__ G, float* __restrict__ Aseg,
                 float* __restrict__ Bseg)
{
    const int j = blockIdx.x * 256 + threadIdx.x;
    const int s = blockIdx.y;
    const int t0 = s * SEGLEN;
    const int t1 = min(t0 + SEGLEN, TSTEPS - 1);
    float A = 1.f, Bv = 0.f;
    for (int t = t0; t < t1; ++t) {
        const float* g = G + (size_t)t * GDIM;
        float iv = sigmoidf_(g[j]);
        float fv = sigmoidf_(g[j + 1024]);
        float gv = tanhf(g[j + 2048]);
        A *= fv;
        Bv = fmaf(fv, Bv, iv * gv);
    }
    Aseg[s * DIM + j] = A;
    Bseg[s * DIM + j] = Bv;
}

__global__ __launch_bounds__(1024)
void dec_scan(const float* __restrict__ Aseg, const float* __restrict__ Bseg,
              float* __restrict__ cinit)
{
    const int j = threadIdx.x;
    float c = 0.f;
    for (int s = 0; s < NSEG; ++s) {
        cinit[s * DIM + j] = c;
        c = fmaf(Aseg[s * DIM + j], c, Bseg[s * DIM + j]);
    }
}

__global__ __launch_bounds__(256)
void dec_emit(const float* __restrict__ G, const float* __restrict__ inp,
              const float* __restrict__ cinit, float* __restrict__ mse_acc)
{
    const int j = blockIdx.x * 256 + threadIdx.x;
    const int s = blockIdx.y;
    const int t0 = s * SEGLEN;
    const int t1 = min(t0 + SEGLEN, TSTEPS - 1);
    float c = cinit[s * DIM + j];
    float acc = 0.f;
    for (int t = t0; t < t1; ++t) {
        const float* g = G + (size_t)t * GDIM;
        float iv = sigmoidf_(g[j]);
        float fv = sigmoidf_(g[j + 1024]);
        float gv = tanhf(g[j + 2048]);
        float ov = sigmoidf_(g[j + 3072]);
        c = fmaf(fv, c, iv * gv);
        float d = ov * tanhf(c);
        float diff = d - inp[(size_t)(t + 1) * DIM + j];
        acc = fmaf(diff, diff, acc);
    }
    #pragma unroll
    for (int off = 32; off >= 1; off >>= 1) acc += __shfl_xor(acc, off);
    if ((threadIdx.x & 63) == 0) atomicAdd(mse_acc, acc);
}

__global__ void finalize(const float* __restrict__ scal, float* __restrict__ out)
{
    float mse = scal[0] / ((float)(TSTEPS - 1) * (float)DIM);
    float l1  = scal[1] / ((float)TSTEPS * (float)DIM);
    out[0] = mse + 0.25f * l1;
    out[1] = mse;
    out[2] = l1;
}

extern "C" void kernel_launch(void* const* d_in, const int* in_sizes, int n_in,
                              void* d_out, int out_size, void* d_ws, size_t ws_size,
                              hipStream_t stream)
{
    const float* inputs  = (const float*)d_in[0];
    const float* enc_Wih = (const float*)d_in[1];
    const float* enc_Whh = (const float*)d_in[2];
    const float* enc_bih = (const float*)d_in[3];
    const float* enc_bhh = (const float*)d_in[4];
    const float* dec_Wih = (const float*)d_in[5];
    const float* dec_Whh = (const float*)d_in[6];
    const float* dec_bih = (const float*)d_in[7];
    const float* dec_bhh = (const float*)d_in[8];
    float* out = (float*)d_out;

    float* ws = (float*)d_ws;
    float* gates  = ws;                            // [4096][4096] Xenc then Gdec
    float* signal = ws + (size_t)16777216;         // [4097][1024] (row 4096 zero)
    unsigned long long* reps =
        (unsigned long long*)(ws + (size_t)20972544);   // [8][2][1024] u64 = 128KB
    float* scal   = ws + (size_t)21005312;         // [mse, l1]
    // decoder scratch aliases the signal buffer (signal is consumed by the
    // DUAL gemm before dec_compose writes here; stream order guarantees it)
    float* Aseg   = signal;                        // [64][1024]
    float* Bseg   = signal + (size_t)65536;        // [64][1024]
    float* cinit  = signal + (size_t)131072;       // [64][1024]
    float* mse_acc = scal + 0;
    float* l1_acc  = scal + 1;

    // one memset: signal row 4096 (1024 f) + reps (32768 f) + scal (8 f)
    hipMemsetAsync(ws + (size_t)20971520, 0, (size_t)(1024 + 32768 + 8) * 4, stream);

    dim3 b256(256);
    // Xenc = inputs @ enc_Wih^T + enc_bih + enc_bhh   (split-bf16 MFMA)
    gemm_split<false><<<dim3(32, 32), b256, 0, stream>>>(
        inputs, enc_Wih, nullptr, nullptr, enc_bih, enc_bhh, gates, GDIM);
    // sequential encoder (fuses L1 accumulation)
    encoder_scan<<<dim3(ENC_NB), dim3(1024), 0, stream>>>(
        gates, enc_Whh, signal, reps, l1_acc);
    // Gdec = signal[1:] @ dec_Wih^T + inputs @ dec_Whh^T + dec biases (fused)
    gemm_split<true><<<dim3(32, 32), b256, 0, stream>>>(
        signal + DIM, dec_Wih, inputs, dec_Whh, dec_bih, dec_bhh, gates, GDIM);
    // decoder segmented scan + mse
    dec_compose<<<dim3(4, NSEG), b256, 0, stream>>>(gates, Aseg, Bseg);
    dec_scan<<<dim3(1), dim3(1024), 0, stream>>>(Aseg, Bseg, cinit);
    dec_emit<<<dim3(4, NSEG), b256, 0, stream>>>(gates, inputs, cinit, mse_acc);
    finalize<<<dim3(1), dim3(1), 0, stream>>>(scal, out);
}